// Round 2
// baseline (2801.604 us; speedup 1.0000x reference)
//
#include <hip/hip_runtime.h>

#define N_NODES 260000
#define N_EDGES 8320000
#define IN_DIM 4
#define H1 26
#define H2 11
#define GRAPH_NODES 26
#define N_GRAPHS 10000

// ---- kernel 0: init s[i] = x[i] (self-loop), deg[i] = 1 ----
__global__ void init_kernel(const float* __restrict__ x, float* __restrict__ s,
                            float* __restrict__ deg) {
    int i = blockIdx.x * blockDim.x + threadIdx.x;
    if (i >= N_NODES) return;
    ((float4*)s)[i] = ((const float4*)x)[i];
    deg[i] = 1.0f;
}

// ---- kernel 1: s[c] += x[r], deg[c] += 1 per edge (4-dim aggregation) ----
__global__ void edge1_kernel(const int* __restrict__ row, const int* __restrict__ col,
                             const float* __restrict__ x, float* __restrict__ s,
                             float* __restrict__ deg) {
    int e = blockIdx.x * blockDim.x + threadIdx.x;
    if (e >= N_EDGES) return;
    int r = row[e];
    int c = col[e];
    float4 xv = ((const float4*)x)[r];
    atomicAdd(&s[c*4+0], xv.x);
    atomicAdd(&s[c*4+1], xv.y);
    atomicAdd(&s[c*4+2], xv.z);
    atomicAdd(&s[c*4+3], xv.w);
    atomicAdd(&deg[c], 1.0f);
}

// ---- kernel 2 (node): agg1 = W1 s + d b1; h1 = tanh; z2' = W2 h1;
//      zbuf = z2'; agg2 = z2' + d*b2 (self-loop + bias of all incoming messages) ----
__global__ void node_kernel(const float* __restrict__ s, const float* __restrict__ deg,
                            const float* __restrict__ W1, const float* __restrict__ b1,
                            const float* __restrict__ W2, const float* __restrict__ b2,
                            float* __restrict__ zbuf, float* __restrict__ agg2) {
    __shared__ float sW1[H1*IN_DIM];
    __shared__ float sb1[H1];
    __shared__ float sW2[H2*H1];
    __shared__ float sb2[H2];
    for (int t = threadIdx.x; t < H1*IN_DIM; t += blockDim.x) sW1[t] = W1[t];
    for (int t = threadIdx.x; t < H1; t += blockDim.x) sb1[t] = b1[t];
    for (int t = threadIdx.x; t < H2*H1; t += blockDim.x) sW2[t] = W2[t];
    for (int t = threadIdx.x; t < H2; t += blockDim.x) sb2[t] = b2[t];
    __syncthreads();
    int i = blockIdx.x * blockDim.x + threadIdx.x;
    if (i >= N_NODES) return;
    float4 sv = ((const float4*)s)[i];
    float d = deg[i];
    float h[H1];
    #pragma unroll
    for (int j = 0; j < H1; ++j) {
        float v = sb1[j]*d + sv.x*sW1[j*4+0] + sv.y*sW1[j*4+1]
                           + sv.z*sW1[j*4+2] + sv.w*sW1[j*4+3];
        h[j] = tanhf(v);
    }
    #pragma unroll
    for (int jj = 0; jj < H2; ++jj) {
        float v = 0.f;
        #pragma unroll
        for (int k = 0; k < H1; ++k) v += h[k] * sW2[jj*H1 + k];
        zbuf[i*H2 + jj] = v;
        agg2[i*H2 + jj] = v + d * sb2[jj];
    }
}

// ---- kernel 3: agg2[c] += zbuf[r] per edge, channel-parallel (16 lanes/edge) ----
__global__ void edge2_kernel(const int* __restrict__ row, const int* __restrict__ col,
                             const float* __restrict__ zbuf, float* __restrict__ agg2) {
    int tid = blockIdx.x * blockDim.x + threadIdx.x;
    int ch = tid & 15;
    int group = tid >> 4;
    int nGroups = (gridDim.x * blockDim.x) >> 4;
    if (ch >= H2) return;
    for (int e = group; e < N_EDGES; e += nGroups) {
        int r = row[e];
        int c = col[e];
        atomicAdd(&agg2[c*H2 + ch], zbuf[r*H2 + ch]);
    }
}

// ---- kernel 4: tanh+maxpool -> per-graph sum -> linear -> softmax ----
__global__ void final_kernel(const float* __restrict__ agg2,
                             const float* __restrict__ Wl, const float* __restrict__ bl,
                             float* __restrict__ out) {
    int tid = blockIdx.x * blockDim.x + threadIdx.x;
    int lane = tid & 31;
    int g = tid >> 5;
    if (g >= N_GRAPHS) return;
    float p0 = 0.f, p1 = 0.f, p2 = 0.f, p3 = 0.f;
    if (lane < GRAPH_NODES) {
        const float* h = agg2 + (size_t)(g*GRAPH_NODES + lane)*H2;
        p0 = tanhf(fmaxf(h[0], h[1]));
        p1 = tanhf(fmaxf(fmaxf(h[2], h[3]), h[4]));
        p2 = tanhf(fmaxf(fmaxf(h[5], h[6]), h[7]));
        p3 = tanhf(fmaxf(fmaxf(h[8], h[9]), h[10]));
    }
    #pragma unroll
    for (int off = 16; off > 0; off >>= 1) {
        p0 += __shfl_down(p0, off, 32);
        p1 += __shfl_down(p1, off, 32);
        p2 += __shfl_down(p2, off, 32);
        p3 += __shfl_down(p3, off, 32);
    }
    if (lane == 0) {
        float o0 = bl[0] + p0*Wl[0] + p1*Wl[1] + p2*Wl[2] + p3*Wl[3];
        float o1 = bl[1] + p0*Wl[4] + p1*Wl[5] + p2*Wl[6] + p3*Wl[7];
        float m = fmaxf(o0, o1);
        float e0 = expf(o0 - m), e1 = expf(o1 - m);
        float ssum = e0 + e1;
        out[g*2 + 0] = e0 / ssum;
        out[g*2 + 1] = e1 / ssum;
    }
}

extern "C" void kernel_launch(void* const* d_in, const int* in_sizes, int n_in,
                              void* d_out, int out_size, void* d_ws, size_t ws_size,
                              hipStream_t stream) {
    const float* x  = (const float*)d_in[0];
    const int* ei   = (const int*)d_in[1];
    const float* W1 = (const float*)d_in[2];
    const float* b1 = (const float*)d_in[3];
    const float* W2 = (const float*)d_in[4];
    const float* b2 = (const float*)d_in[5];
    const float* Wl = (const float*)d_in[6];
    const float* bl = (const float*)d_in[7];
    float* out = (float*)d_out;

    const int* row = ei;            // edge_index[0]
    const int* col = ei + N_EDGES;  // edge_index[1]

    // workspace (floats):
    //   s:    [0, 1,040,000)                4 ch sums
    //   deg:  [1,040,000, 1,300,000)        message counts (incl self-loop)
    //   zbuf: [1,300,000, 4,160,000)        z2' = W2 h1   (11 ch)
    //   agg2: [4,160,000, 7,020,000)        layer-2 aggregate (11 ch)  ~28 MB
    float* ws   = (float*)d_ws;
    float* s    = ws;
    float* deg  = ws + (size_t)N_NODES * IN_DIM;
    float* zbuf = deg + N_NODES;
    float* agg2 = zbuf + (size_t)N_NODES * H2;

    dim3 blk(256);
    int nodeBlocks = (N_NODES + 255) / 256;
    int edgeBlocks = (N_EDGES + 255) / 256;

    init_kernel<<<nodeBlocks, blk, 0, stream>>>(x, s, deg);
    edge1_kernel<<<edgeBlocks, blk, 0, stream>>>(row, col, x, s, deg);
    node_kernel<<<nodeBlocks, blk, 0, stream>>>(s, deg, W1, b1, W2, b2, zbuf, agg2);
    edge2_kernel<<<4096, blk, 0, stream>>>(row, col, zbuf, agg2);
    final_kernel<<<(N_GRAPHS*32 + 255)/256, blk, 0, stream>>>(agg2, Wl, bl, out);
}

// Round 4
// 1154.024 us; speedup vs baseline: 2.4277x; 2.4277x over previous
//
#include <hip/hip_runtime.h>

#define N_NODES 260000
#define N_EDGES 8320000
#define H1 26
#define H2 11
#define GRAPH_NODES 26
#define N_GRAPHS 10000

#define NB 512            // nodes per bucket
#define NBUCK 508         // ceil(260000/512)
#define NPB 1024          // partition blocks
#define EPB 8125          // edges per partition block (1024*8125 == 8320000)
#define ZSTRIDE 12        // zbuf floats per node (11 ch + deg)

// ---- zero ghist(512) + gpool(40000) ----
__global__ __launch_bounds__(256) void zero_kernel(unsigned* __restrict__ ghist,
                                                   float* __restrict__ gpool) {
    int i = blockIdx.x * 256 + threadIdx.x;
    if (i < 512) ghist[i] = 0u;
    if (i < N_GRAPHS * 4) gpool[i] = 0.f;
}

// ---- count: global bucket histogram via per-block LDS histograms ----
__global__ __launch_bounds__(256) void count_kernel(const int* __restrict__ col,
                                                    unsigned* __restrict__ ghist) {
    __shared__ unsigned lh[NBUCK];
    for (int b = threadIdx.x; b < NBUCK; b += 256) lh[b] = 0u;
    __syncthreads();
    int stride = gridDim.x * blockDim.x;
    for (int e = blockIdx.x * blockDim.x + threadIdx.x; e < N_EDGES; e += stride)
        atomicAdd(&lh[((unsigned)col[e]) >> 9], 1u);
    __syncthreads();
    for (int b = threadIdx.x; b < NBUCK; b += 256)
        if (lh[b]) atomicAdd(&ghist[b], lh[b]);
}

// ---- exclusive scan of 508 bucket counts (single block) ----
__global__ __launch_bounds__(512) void scan_kernel(const unsigned* __restrict__ ghist,
                                                   unsigned* __restrict__ bstart,
                                                   unsigned* __restrict__ bfill) {
    __shared__ unsigned v[512];
    int t = threadIdx.x;
    v[t] = (t < NBUCK) ? ghist[t] : 0u;
    __syncthreads();
    for (int off = 1; off < 512; off <<= 1) {
        unsigned add = (t >= off) ? v[t - off] : 0u;
        __syncthreads();
        v[t] += add;
        __syncthreads();
    }
    if (t < NBUCK) {
        unsigned st = (t == 0) ? 0u : v[t - 1];
        bstart[t] = st;
        bfill[t]  = st;
        if (t == NBUCK - 1) bstart[NBUCK] = v[t];   // == N_EDGES
    }
}

// ---- partition: place packed (r<<9 | c&511) into bucket-grouped array ----
__global__ __launch_bounds__(256) void place_kernel(const int* __restrict__ row,
                                                    const int* __restrict__ col,
                                                    unsigned* __restrict__ bfill,
                                                    unsigned* __restrict__ part) {
    __shared__ unsigned lh[NBUCK];
    __shared__ unsigned lbase[NBUCK];
    for (int b = threadIdx.x; b < NBUCK; b += 256) lh[b] = 0u;
    __syncthreads();
    int e0 = blockIdx.x * EPB;
    int e1 = e0 + EPB;
    for (int e = e0 + threadIdx.x; e < e1; e += 256)
        atomicAdd(&lh[((unsigned)col[e]) >> 9], 1u);
    __syncthreads();
    for (int b = threadIdx.x; b < NBUCK; b += 256) {
        unsigned c = lh[b];
        lbase[b] = c ? atomicAdd(&bfill[b], c) : 0u;
    }
    __syncthreads();
    for (int b = threadIdx.x; b < NBUCK; b += 256) lh[b] = 0u;
    __syncthreads();
    for (int e = e0 + threadIdx.x; e < e1; e += 256) {
        unsigned c = (unsigned)col[e];
        unsigned b = c >> 9;
        unsigned p = lbase[b] + atomicAdd(&lh[b], 1u);
        part[p] = (((unsigned)row[e]) << 9) | (c & 511u);
    }
}

// ---- layer 1 per bucket: LDS 4-dim sums + deg -> h1 -> z2' -> zbuf(+deg) ----
__global__ __launch_bounds__(256) void layer1_kernel(const unsigned* __restrict__ part,
                                                     const unsigned* __restrict__ bstart,
                                                     const float* __restrict__ x,
                                                     const float* __restrict__ W1,
                                                     const float* __restrict__ b1,
                                                     const float* __restrict__ W2,
                                                     const float* __restrict__ b2,
                                                     float* __restrict__ zbuf) {
    __shared__ float acc[NB][5];
    __shared__ float sW1[H1 * 4], sb1[H1], sW2[H2 * H1];
    for (int t = threadIdx.x; t < H1 * 4; t += 256) sW1[t] = W1[t];
    for (int t = threadIdx.x; t < H1; t += 256) sb1[t] = b1[t];
    for (int t = threadIdx.x; t < H2 * H1; t += 256) sW2[t] = W2[t];
    for (int t = threadIdx.x; t < NB * 5; t += 256) ((float*)acc)[t] = 0.f;
    __syncthreads();
    unsigned s = bstart[blockIdx.x], e = bstart[blockIdx.x + 1];
    for (unsigned i = s + threadIdx.x; i < e; i += 256) {
        unsigned u = part[i];
        unsigned r = u >> 9, cl = u & 511u;
        float4 xv = ((const float4*)x)[r];
        atomicAdd(&acc[cl][0], xv.x);
        atomicAdd(&acc[cl][1], xv.y);
        atomicAdd(&acc[cl][2], xv.z);
        atomicAdd(&acc[cl][3], xv.w);
        atomicAdd(&acc[cl][4], 1.f);
    }
    __syncthreads();
    int base = blockIdx.x * NB;
    for (int n = threadIdx.x; n < NB; n += 256) {
        int node = base + n;
        if (node >= N_NODES) continue;
        float4 xv = ((const float4*)x)[node];      // self-loop
        float sx = acc[n][0] + xv.x, sy = acc[n][1] + xv.y;
        float sz = acc[n][2] + xv.z, sw = acc[n][3] + xv.w;
        float deg = acc[n][4] + 1.f;
        float h[H1];
        #pragma unroll
        for (int j = 0; j < H1; ++j)
            h[j] = tanhf(sb1[j] * deg + sx * sW1[j*4+0] + sy * sW1[j*4+1]
                                      + sz * sW1[j*4+2] + sw * sW1[j*4+3]);
        float* zp = zbuf + (size_t)node * ZSTRIDE;
        #pragma unroll
        for (int jj = 0; jj < H2; ++jj) {
            float v = 0.f;
            #pragma unroll
            for (int k = 0; k < H1; ++k) v += h[k] * sW2[jj*H1 + k];
            zp[jj] = v;                            // z2' = W2 h1 (no bias)
        }
        zp[H2] = deg;                              // stash deg as 12th value
    }
}

// ---- layer 2 per bucket: LDS accumulate z2' messages, then pool + graph sum ----
__global__ __launch_bounds__(256) void layer2_kernel(const unsigned* __restrict__ part,
                                                     const unsigned* __restrict__ bstart,
                                                     const float* __restrict__ zbuf,
                                                     const float* __restrict__ b2,
                                                     float* __restrict__ gpool) {
    __shared__ float facc[NB][ZSTRIDE];            // 24 KB
    __shared__ float sb2[H2];
    __shared__ float gacc[22][4];
    if (threadIdx.x < H2) sb2[threadIdx.x] = b2[threadIdx.x];
    if (threadIdx.x < 88) ((float*)gacc)[threadIdx.x] = 0.f;
    // init: copy this bucket's zbuf slice (contiguous, coalesced)
    const float* zslice = zbuf + (size_t)blockIdx.x * NB * ZSTRIDE;
    for (int t = threadIdx.x; t < NB * ZSTRIDE; t += 256)
        ((float*)facc)[t] = zslice[t];
    __syncthreads();
    // self-loop + bias: facc[n][ch] = z'_n[ch] + deg_n * b2[ch]
    for (int t = threadIdx.x; t < NB * ZSTRIDE; t += 256) {
        int n = t / ZSTRIDE, ch = t - n * ZSTRIDE;
        if (ch < H2) facc[n][ch] += facc[n][H2] * sb2[ch];
    }
    __syncthreads();
    // edge accumulation: 16 lanes per edge, ch<11 active
    unsigned s = bstart[blockIdx.x], e = bstart[blockIdx.x + 1];
    int ch = threadIdx.x & 15;
    int sub = threadIdx.x >> 4;                    // 0..15 edge groups
    for (unsigned i = s + sub; i < e; i += 16) {
        unsigned u = part[i];
        unsigned r = u >> 9, cl = u & 511u;
        if (ch < H2) atomicAdd(&facc[cl][ch], zbuf[(size_t)r * ZSTRIDE + ch]);
    }
    __syncthreads();
    // tanh + maxpool + per-graph partial sums (LDS), then few global atomics
    int base = blockIdx.x * NB;
    int gfirst = base / GRAPH_NODES;
    int lastnode = min(base + NB - 1, N_NODES - 1);
    int glast = lastnode / GRAPH_NODES;
    for (int n = threadIdx.x; n < NB; n += 256) {
        int node = base + n;
        if (node >= N_NODES) continue;
        const float* h = facc[n];
        float p0 = tanhf(fmaxf(h[0], h[1]));
        float p1 = tanhf(fmaxf(fmaxf(h[2], h[3]), h[4]));
        float p2 = tanhf(fmaxf(fmaxf(h[5], h[6]), h[7]));
        float p3 = tanhf(fmaxf(fmaxf(h[8], h[9]), h[10]));
        int lg = node / GRAPH_NODES - gfirst;
        atomicAdd(&gacc[lg][0], p0);
        atomicAdd(&gacc[lg][1], p1);
        atomicAdd(&gacc[lg][2], p2);
        atomicAdd(&gacc[lg][3], p3);
    }
    __syncthreads();
    int ng = glast - gfirst + 1;
    for (int t = threadIdx.x; t < ng * 4; t += 256) {
        int lg = t >> 2, c = t & 3;
        float v = gacc[lg][c];
        if (v != 0.f) atomicAdd(&gpool[(size_t)(gfirst + lg) * 4 + c], v);
    }
}

// ---- final: linear + softmax per graph ----
__global__ __launch_bounds__(256) void final_kernel(const float* __restrict__ gpool,
                                                    const float* __restrict__ Wl,
                                                    const float* __restrict__ bl,
                                                    float* __restrict__ out) {
    int g = blockIdx.x * 256 + threadIdx.x;
    if (g >= N_GRAPHS) return;
    float4 p = ((const float4*)gpool)[g];
    float o0 = bl[0] + p.x * Wl[0] + p.y * Wl[1] + p.z * Wl[2] + p.w * Wl[3];
    float o1 = bl[1] + p.x * Wl[4] + p.y * Wl[5] + p.z * Wl[6] + p.w * Wl[7];
    float m = fmaxf(o0, o1);
    float e0 = expf(o0 - m), e1 = expf(o1 - m);
    float s = e0 + e1;
    out[g * 2 + 0] = e0 / s;
    out[g * 2 + 1] = e1 / s;
}

extern "C" void kernel_launch(void* const* d_in, const int* in_sizes, int n_in,
                              void* d_out, int out_size, void* d_ws, size_t ws_size,
                              hipStream_t stream) {
    const float* x  = (const float*)d_in[0];
    const int* ei   = (const int*)d_in[1];
    const float* W1 = (const float*)d_in[2];
    const float* b1 = (const float*)d_in[3];
    const float* W2 = (const float*)d_in[4];
    const float* b2 = (const float*)d_in[5];
    const float* Wl = (const float*)d_in[6];
    const float* bl = (const float*)d_in[7];
    float* out = (float*)d_out;

    const int* row = ei;            // edge_index[0] (source)
    const int* col = ei + N_EDGES;  // edge_index[1] (destination)

    // ws layout (floats): zbuf 3,121,152 | part 8,320,000 | bstart 512 |
    //                     bfill 512 | ghist 512 | gpool 40,000  => ~45.9 MB
    float*    ws     = (float*)d_ws;
    float*    zbuf   = ws;
    unsigned* part   = (unsigned*)(ws + (size_t)NBUCK * NB * ZSTRIDE);
    unsigned* bstart = part + N_EDGES;
    unsigned* bfill  = bstart + 512;
    unsigned* ghist  = bfill + 512;
    float*    gpool  = (float*)(ghist + 512);

    zero_kernel<<<(N_GRAPHS*4 + 255)/256, 256, 0, stream>>>(ghist, gpool);
    count_kernel<<<NPB, 256, 0, stream>>>(col, ghist);
    scan_kernel<<<1, 512, 0, stream>>>(ghist, bstart, bfill);
    place_kernel<<<NPB, 256, 0, stream>>>(row, col, bfill, part);
    layer1_kernel<<<NBUCK, 256, 0, stream>>>(part, bstart, x, W1, b1, W2, b2, zbuf);
    layer2_kernel<<<NBUCK, 256, 0, stream>>>(part, bstart, zbuf, b2, gpool);
    final_kernel<<<(N_GRAPHS + 255)/256, 256, 0, stream>>>(gpool, Wl, bl, out);
}

// Round 5
// 1072.343 us; speedup vs baseline: 2.6126x; 1.0762x over previous
//
#include <hip/hip_runtime.h>

#define N_NODES 260000
#define N_EDGES 8320000
#define H1 26
#define H2 11
#define GRAPH_NODES 26
#define N_GRAPHS 10000

#define NB 128            // nodes per bucket
#define NBUCK 2032        // ceil(260000/128)
#define NPB 1024          // partition blocks
#define EPB 8125          // edges per partition block (1024*8125 == 8320000)
#define ZSTRIDE 12        // zmsg floats per node (11 ch + deg), 48 B rows
#define FSTRIDE 13        // facc LDS stride (coprime with 32 banks)

// ---- zero ghist + gpool ----
__global__ __launch_bounds__(256) void zero_kernel(unsigned* __restrict__ ghist,
                                                   float* __restrict__ gpool) {
    int i = blockIdx.x * 256 + threadIdx.x;
    if (i < NBUCK) ghist[i] = 0u;
    if (i < N_GRAPHS * 4) gpool[i] = 0.f;
}

// ---- count: global bucket histogram via per-block LDS histograms ----
__global__ __launch_bounds__(256) void count_kernel(const int* __restrict__ col,
                                                    unsigned* __restrict__ ghist) {
    __shared__ unsigned lh[NBUCK];
    for (int b = threadIdx.x; b < NBUCK; b += 256) lh[b] = 0u;
    __syncthreads();
    int stride = gridDim.x * blockDim.x;
    for (int e = blockIdx.x * blockDim.x + threadIdx.x; e < N_EDGES; e += stride)
        atomicAdd(&lh[((unsigned)col[e]) >> 7], 1u);
    __syncthreads();
    for (int b = threadIdx.x; b < NBUCK; b += 256)
        if (lh[b]) atomicAdd(&ghist[b], lh[b]);
}

// ---- exclusive scan of 2032 bucket counts (single 1024-thread block) ----
__global__ __launch_bounds__(1024) void scan_kernel(const unsigned* __restrict__ ghist,
                                                    unsigned* __restrict__ bstart,
                                                    unsigned* __restrict__ bfill) {
    __shared__ unsigned v[2048];
    int t = threadIdx.x;
    int t1 = t + 1024;
    v[t]  = (t  < NBUCK) ? ghist[t]  : 0u;
    v[t1] = (t1 < NBUCK) ? ghist[t1] : 0u;
    __syncthreads();
    for (int off = 1; off < 2048; off <<= 1) {
        unsigned a0 = (t  >= off) ? v[t  - off] : 0u;
        unsigned a1 = (t1 >= off) ? v[t1 - off] : 0u;
        __syncthreads();
        v[t]  += a0;
        v[t1] += a1;
        __syncthreads();
    }
    if (t < NBUCK) {
        unsigned st = (t == 0) ? 0u : v[t - 1];
        bstart[t] = st; bfill[t] = st;
    }
    if (t1 < NBUCK) {
        unsigned st = v[t1 - 1];
        bstart[t1] = st; bfill[t1] = st;
        if (t1 == NBUCK - 1) bstart[NBUCK] = v[t1];
    }
}

// ---- partition: place packed (r<<7 | c&127) into bucket-grouped array ----
__global__ __launch_bounds__(256) void place_kernel(const int* __restrict__ row,
                                                    const int* __restrict__ col,
                                                    unsigned* __restrict__ bfill,
                                                    unsigned* __restrict__ part) {
    __shared__ unsigned lh[NBUCK];
    __shared__ unsigned lbase[NBUCK];
    for (int b = threadIdx.x; b < NBUCK; b += 256) lh[b] = 0u;
    __syncthreads();
    int e0 = blockIdx.x * EPB;
    int e1 = e0 + EPB;
    for (int e = e0 + threadIdx.x; e < e1; e += 256)
        atomicAdd(&lh[((unsigned)col[e]) >> 7], 1u);
    __syncthreads();
    for (int b = threadIdx.x; b < NBUCK; b += 256) {
        unsigned c = lh[b];
        lbase[b] = c ? atomicAdd(&bfill[b], c) : 0u;
    }
    __syncthreads();
    for (int b = threadIdx.x; b < NBUCK; b += 256) lh[b] = 0u;
    __syncthreads();
    for (int e = e0 + threadIdx.x; e < e1; e += 256) {
        unsigned c = (unsigned)col[e];
        unsigned b = c >> 7;
        unsigned p = lbase[b] + atomicAdd(&lh[b], 1u);
        part[p] = (((unsigned)row[e]) << 7) | (c & 127u);
    }
}

// ---- layer 1 per bucket: LDS 4-dim sums + deg -> h1 -> z2' -> zmsg ----
__global__ __launch_bounds__(256) void layer1_kernel(const unsigned* __restrict__ part,
                                                     const unsigned* __restrict__ bstart,
                                                     const float* __restrict__ x,
                                                     const float* __restrict__ W1,
                                                     const float* __restrict__ b1,
                                                     const float* __restrict__ W2,
                                                     const float* __restrict__ b2,
                                                     float* __restrict__ zmsg) {
    __shared__ float acc[NB * 5];
    __shared__ float sW1[H1 * 4], sb1[H1], sW2[H2 * H1];
    for (int t = threadIdx.x; t < H1 * 4; t += 256) sW1[t] = W1[t];
    for (int t = threadIdx.x; t < H1; t += 256) sb1[t] = b1[t];
    for (int t = threadIdx.x; t < H2 * H1; t += 256) sW2[t] = W2[t];
    for (int t = threadIdx.x; t < NB * 5; t += 256) acc[t] = 0.f;
    __syncthreads();
    unsigned s = bstart[blockIdx.x], e = bstart[blockIdx.x + 1];
    for (unsigned i = s + threadIdx.x; i < e; i += 256) {
        unsigned u = part[i];
        unsigned r = u >> 7, cl = u & 127u;
        float4 xv = ((const float4*)x)[r];
        atomicAdd(&acc[cl*5+0], xv.x);
        atomicAdd(&acc[cl*5+1], xv.y);
        atomicAdd(&acc[cl*5+2], xv.z);
        atomicAdd(&acc[cl*5+3], xv.w);
        atomicAdd(&acc[cl*5+4], 1.f);
    }
    __syncthreads();
    int base = blockIdx.x * NB;
    for (int n = threadIdx.x; n < NB; n += 256) {
        int node = base + n;
        if (node >= N_NODES) continue;
        float4 xv = ((const float4*)x)[node];      // self-loop
        float sx = acc[n*5+0] + xv.x, sy = acc[n*5+1] + xv.y;
        float sz = acc[n*5+2] + xv.z, sw = acc[n*5+3] + xv.w;
        float deg = acc[n*5+4] + 1.f;
        float h[H1];
        #pragma unroll
        for (int j = 0; j < H1; ++j)
            h[j] = tanhf(sb1[j] * deg + sx * sW1[j*4+0] + sy * sW1[j*4+1]
                                      + sz * sW1[j*4+2] + sw * sW1[j*4+3]);
        float* zp = zmsg + (size_t)node * ZSTRIDE;
        #pragma unroll
        for (int jj = 0; jj < H2; ++jj) {
            float v = 0.f;
            #pragma unroll
            for (int k = 0; k < H1; ++k) v += h[k] * sW2[jj*H1 + k];
            zp[jj] = v;                            // z2' = W2 h1 (no bias)
        }
        zp[H2] = deg;                              // deg in slot 11
    }
}

// ---- layer 2 per bucket: per-thread edge gather + LDS accumulate; pool fused ----
__global__ __launch_bounds__(256) void layer2_kernel(const unsigned* __restrict__ part,
                                                     const unsigned* __restrict__ bstart,
                                                     const float* __restrict__ zmsg,
                                                     const float* __restrict__ b2,
                                                     float* __restrict__ gpool) {
    __shared__ float facc[NB * FSTRIDE];           // 6.7 KB
    __shared__ float sb2[H2];
    __shared__ float gacc[7][4];
    if (threadIdx.x < H2) sb2[threadIdx.x] = b2[threadIdx.x];
    if (threadIdx.x < 28) ((float*)gacc)[threadIdx.x] = 0.f;
    // init: copy this bucket's zmsg slice (coalesced); ch 0..10 = z', 11 = deg
    const float* zslice = zmsg + (size_t)blockIdx.x * NB * ZSTRIDE;
    for (int t = threadIdx.x; t < NB * ZSTRIDE; t += 256) {
        int n = t / ZSTRIDE, ch = t - n * ZSTRIDE;
        facc[n * FSTRIDE + ch] = zslice[t];
    }
    __syncthreads();
    // self-loop + bias: facc[n][ch] += deg_n * b2[ch]
    for (int t = threadIdx.x; t < NB * H2; t += 256) {
        int n = t / H2, ch = t - n * H2;
        facc[n * FSTRIDE + ch] += facc[n * FSTRIDE + H2] * sb2[ch];
    }
    __syncthreads();
    // edge accumulation: one edge per thread, 3x float4 gather
    unsigned s = bstart[blockIdx.x], e = bstart[blockIdx.x + 1];
    for (unsigned i = s + threadIdx.x; i < e; i += 256) {
        unsigned u = part[i];
        unsigned r = u >> 7, cl = u & 127u;
        const float4* z4 = (const float4*)(zmsg + (size_t)r * ZSTRIDE);
        float4 a = z4[0], b = z4[1], c = z4[2];
        float* f = facc + cl * FSTRIDE;
        atomicAdd(&f[0],  a.x); atomicAdd(&f[1],  a.y);
        atomicAdd(&f[2],  a.z); atomicAdd(&f[3],  a.w);
        atomicAdd(&f[4],  b.x); atomicAdd(&f[5],  b.y);
        atomicAdd(&f[6],  b.z); atomicAdd(&f[7],  b.w);
        atomicAdd(&f[8],  c.x); atomicAdd(&f[9],  c.y);
        atomicAdd(&f[10], c.z);
    }
    __syncthreads();
    // tanh + maxpool + per-graph partial sums (LDS), then few global atomics
    int base = blockIdx.x * NB;
    int gfirst = base / GRAPH_NODES;
    int lastnode = min(base + NB - 1, N_NODES - 1);
    int glast = lastnode / GRAPH_NODES;
    for (int n = threadIdx.x; n < NB; n += 256) {
        int node = base + n;
        if (node >= N_NODES) continue;
        const float* h = facc + n * FSTRIDE;
        float p0 = tanhf(fmaxf(h[0], h[1]));
        float p1 = tanhf(fmaxf(fmaxf(h[2], h[3]), h[4]));
        float p2 = tanhf(fmaxf(fmaxf(h[5], h[6]), h[7]));
        float p3 = tanhf(fmaxf(fmaxf(h[8], h[9]), h[10]));
        int lg = node / GRAPH_NODES - gfirst;
        atomicAdd(&gacc[lg][0], p0);
        atomicAdd(&gacc[lg][1], p1);
        atomicAdd(&gacc[lg][2], p2);
        atomicAdd(&gacc[lg][3], p3);
    }
    __syncthreads();
    int ng = glast - gfirst + 1;
    for (int t = threadIdx.x; t < ng * 4; t += 256) {
        int lg = t >> 2, c = t & 3;
        float v = gacc[lg][c];
        if (v != 0.f) atomicAdd(&gpool[(size_t)(gfirst + lg) * 4 + c], v);
    }
}

// ---- final: linear + softmax per graph ----
__global__ __launch_bounds__(256) void final_kernel(const float* __restrict__ gpool,
                                                    const float* __restrict__ Wl,
                                                    const float* __restrict__ bl,
                                                    float* __restrict__ out) {
    int g = blockIdx.x * 256 + threadIdx.x;
    if (g >= N_GRAPHS) return;
    float4 p = ((const float4*)gpool)[g];
    float o0 = bl[0] + p.x * Wl[0] + p.y * Wl[1] + p.z * Wl[2] + p.w * Wl[3];
    float o1 = bl[1] + p.x * Wl[4] + p.y * Wl[5] + p.z * Wl[6] + p.w * Wl[7];
    float m = fmaxf(o0, o1);
    float e0 = expf(o0 - m), e1 = expf(o1 - m);
    float s = e0 + e1;
    out[g * 2 + 0] = e0 / s;
    out[g * 2 + 1] = e1 / s;
}

extern "C" void kernel_launch(void* const* d_in, const int* in_sizes, int n_in,
                              void* d_out, int out_size, void* d_ws, size_t ws_size,
                              hipStream_t stream) {
    const float* x  = (const float*)d_in[0];
    const int* ei   = (const int*)d_in[1];
    const float* W1 = (const float*)d_in[2];
    const float* b1 = (const float*)d_in[3];
    const float* W2 = (const float*)d_in[4];
    const float* b2 = (const float*)d_in[5];
    const float* Wl = (const float*)d_in[6];
    const float* bl = (const float*)d_in[7];
    float* out = (float*)d_out;

    const int* row = ei;            // edge_index[0] (source)
    const int* col = ei + N_EDGES;  // edge_index[1] (destination)

    // ws layout (floats): zmsg 3,121,152 | part 8,320,000 | bstart 2,049 |
    //                     bfill 2,032 | ghist 2,032 | gpool 40,000  => ~45.9 MB
    float*    ws     = (float*)d_ws;
    float*    zmsg   = ws;
    unsigned* part   = (unsigned*)(ws + (size_t)(NBUCK * NB) * ZSTRIDE);
    unsigned* bstart = part + N_EDGES;
    unsigned* bfill  = bstart + NBUCK + 1;
    unsigned* ghist  = bfill + NBUCK;
    float*    gpool  = (float*)(ghist + NBUCK);

    zero_kernel<<<(N_GRAPHS*4 + 255)/256, 256, 0, stream>>>(ghist, gpool);
    count_kernel<<<NPB, 256, 0, stream>>>(col, ghist);
    scan_kernel<<<1, 1024, 0, stream>>>(ghist, bstart, bfill);
    place_kernel<<<NPB, 256, 0, stream>>>(row, col, bfill, part);
    layer1_kernel<<<NBUCK, 256, 0, stream>>>(part, bstart, x, W1, b1, W2, b2, zmsg);
    layer2_kernel<<<NBUCK, 256, 0, stream>>>(part, bstart, zmsg, b2, gpool);
    final_kernel<<<(N_GRAPHS + 255)/256, 256, 0, stream>>>(gpool, Wl, bl, out);
}

// Round 6
// 1003.044 us; speedup vs baseline: 2.7931x; 1.0691x over previous
//
#include <hip/hip_runtime.h>
#include <hip/hip_fp16.h>

#define N_NODES 260000
#define N_EDGES 8320000
#define H1 26
#define H2 11
#define GRAPH_NODES 26
#define N_GRAPHS 10000

#define NB 128            // nodes per bucket
#define NBUCK 2032        // ceil(260000/128)
#define NPB 256           // partition/count blocks
#define PBT 1024          // partition/count block threads
#define EPB 32500         // edges per partition block (256*32500 == 8,320,000)
#define ZS 16             // zmsg ushorts per node: 11 fp16 ch + fp16 deg + 4 pad = 32 B
#define FSTRIDE 13        // facc LDS stride (coprime with 32 banks)

__device__ __forceinline__ float2 up2(unsigned u) {
    __half2 h = *reinterpret_cast<const __half2*>(&u);
    return __half22float2(h);
}
__device__ __forceinline__ unsigned pk2(float a, float b) {
    __half2 h = __floats2half2_rn(a, b);
    return *reinterpret_cast<const unsigned*>(&h);
}

// ---- zero ghist + gpool ----
__global__ __launch_bounds__(256) void zero_kernel(unsigned* __restrict__ ghist,
                                                   float* __restrict__ gpool) {
    int i = blockIdx.x * 256 + threadIdx.x;
    if (i < NBUCK) ghist[i] = 0u;
    if (i < N_GRAPHS * 4) gpool[i] = 0.f;
}

// ---- count: bucket histogram via per-block LDS histograms ----
__global__ __launch_bounds__(PBT) void count_kernel(const int* __restrict__ col,
                                                    unsigned* __restrict__ ghist) {
    __shared__ unsigned lh[NBUCK];
    for (int b = threadIdx.x; b < NBUCK; b += PBT) lh[b] = 0u;
    __syncthreads();
    int e0 = blockIdx.x * EPB, e1 = e0 + EPB;
    for (int e = e0 + threadIdx.x; e < e1; e += PBT)
        atomicAdd(&lh[((unsigned)col[e]) >> 7], 1u);
    __syncthreads();
    for (int b = threadIdx.x; b < NBUCK; b += PBT)
        if (lh[b]) atomicAdd(&ghist[b], lh[b]);
}

// ---- exclusive scan of 2032 bucket counts (single 1024-thread block) ----
__global__ __launch_bounds__(1024) void scan_kernel(const unsigned* __restrict__ ghist,
                                                    unsigned* __restrict__ bstart,
                                                    unsigned* __restrict__ bfill) {
    __shared__ unsigned v[2048];
    int t = threadIdx.x;
    int t1 = t + 1024;
    v[t]  = (t  < NBUCK) ? ghist[t]  : 0u;
    v[t1] = (t1 < NBUCK) ? ghist[t1] : 0u;
    __syncthreads();
    for (int off = 1; off < 2048; off <<= 1) {
        unsigned a0 = (t  >= off) ? v[t  - off] : 0u;
        unsigned a1 = (t1 >= off) ? v[t1 - off] : 0u;
        __syncthreads();
        v[t]  += a0;
        v[t1] += a1;
        __syncthreads();
    }
    if (t < NBUCK) {
        unsigned st = (t == 0) ? 0u : v[t - 1];
        bstart[t] = st; bfill[t] = st;
    }
    if (t1 < NBUCK) {
        unsigned st = v[t1 - 1];
        bstart[t1] = st; bfill[t1] = st;
        if (t1 == NBUCK - 1) bstart[NBUCK] = v[t1];
    }
}

// ---- partition: place packed (r<<7 | c&127) into bucket-grouped array ----
__global__ __launch_bounds__(PBT) void place_kernel(const int* __restrict__ row,
                                                    const int* __restrict__ col,
                                                    unsigned* __restrict__ bfill,
                                                    unsigned* __restrict__ part) {
    __shared__ unsigned lh[NBUCK];
    __shared__ unsigned lbase[NBUCK];
    for (int b = threadIdx.x; b < NBUCK; b += PBT) lh[b] = 0u;
    __syncthreads();
    int e0 = blockIdx.x * EPB, e1 = e0 + EPB;
    for (int e = e0 + threadIdx.x; e < e1; e += PBT)
        atomicAdd(&lh[((unsigned)col[e]) >> 7], 1u);
    __syncthreads();
    for (int b = threadIdx.x; b < NBUCK; b += PBT) {
        unsigned c = lh[b];
        lbase[b] = c ? atomicAdd(&bfill[b], c) : 0u;
    }
    __syncthreads();
    for (int b = threadIdx.x; b < NBUCK; b += PBT) lh[b] = 0u;
    __syncthreads();
    for (int e = e0 + threadIdx.x; e < e1; e += PBT) {
        unsigned c = (unsigned)col[e];
        unsigned b = c >> 7;
        unsigned p = lbase[b] + atomicAdd(&lh[b], 1u);
        part[p] = (((unsigned)row[e]) << 7) | (c & 127u);
    }
}

__device__ __forceinline__ void acc_node(float* acc, unsigned cl, float4 xv) {
    float* a = acc + cl * 5;
    atomicAdd(&a[0], xv.x); atomicAdd(&a[1], xv.y);
    atomicAdd(&a[2], xv.z); atomicAdd(&a[3], xv.w);
    atomicAdd(&a[4], 1.f);
}

// ---- layer 1 per bucket: LDS 4-dim sums + deg -> h1 -> z2' -> fp16 zmsg ----
__global__ __launch_bounds__(256) void layer1_kernel(const unsigned* __restrict__ part,
                                                     const unsigned* __restrict__ bstart,
                                                     const float* __restrict__ x,
                                                     const float* __restrict__ W1,
                                                     const float* __restrict__ b1,
                                                     const float* __restrict__ W2,
                                                     const float* __restrict__ b2,
                                                     ushort* __restrict__ zmsg) {
    __shared__ float acc[NB * 5];
    __shared__ float sW1[H1 * 4], sb1[H1], sW2[H2 * H1];
    for (int t = threadIdx.x; t < H1 * 4; t += 256) sW1[t] = W1[t];
    for (int t = threadIdx.x; t < H1; t += 256) sb1[t] = b1[t];
    for (int t = threadIdx.x; t < H2 * H1; t += 256) sW2[t] = W2[t];
    for (int t = threadIdx.x; t < NB * 5; t += 256) acc[t] = 0.f;
    __syncthreads();
    unsigned s = bstart[blockIdx.x], e = bstart[blockIdx.x + 1];
    unsigned i = s + threadIdx.x;
    for (; i + 256 < e; i += 512) {
        unsigned u1 = part[i], u2 = part[i + 256];
        unsigned r1 = u1 >> 7, cl1 = u1 & 127u;
        unsigned r2 = u2 >> 7, cl2 = u2 & 127u;
        float4 x1 = ((const float4*)x)[r1];
        float4 x2 = ((const float4*)x)[r2];
        acc_node(acc, cl1, x1);
        acc_node(acc, cl2, x2);
    }
    if (i < e) {
        unsigned u = part[i];
        acc_node(acc, u & 127u, ((const float4*)x)[u >> 7]);
    }
    __syncthreads();
    int base = blockIdx.x * NB;
    for (int n = threadIdx.x; n < NB; n += 256) {
        int node = base + n;
        if (node >= N_NODES) continue;
        float4 xv = ((const float4*)x)[node];      // self-loop
        float sx = acc[n*5+0] + xv.x, sy = acc[n*5+1] + xv.y;
        float sz = acc[n*5+2] + xv.z, sw = acc[n*5+3] + xv.w;
        float deg = acc[n*5+4] + 1.f;
        float h[H1];
        #pragma unroll
        for (int j = 0; j < H1; ++j)
            h[j] = tanhf(sb1[j] * deg + sx * sW1[j*4+0] + sy * sW1[j*4+1]
                                      + sz * sW1[j*4+2] + sw * sW1[j*4+3]);
        float z[H2];
        #pragma unroll
        for (int jj = 0; jj < H2; ++jj) {
            float v = 0.f;
            #pragma unroll
            for (int k = 0; k < H1; ++k) v += h[k] * sW2[jj*H1 + k];
            z[jj] = v;                             // z2' = W2 h1 (no bias)
        }
        uint4 lo, hi;
        lo.x = pk2(z[0], z[1]);  lo.y = pk2(z[2], z[3]);
        lo.z = pk2(z[4], z[5]);  lo.w = pk2(z[6], z[7]);
        hi.x = pk2(z[8], z[9]);  hi.y = pk2(z[10], deg);
        hi.z = 0u; hi.w = 0u;
        uint4* zp = (uint4*)(zmsg + (size_t)node * ZS);
        zp[0] = lo;
        zp[1] = hi;
    }
}

__device__ __forceinline__ void acc_edge(float* facc, unsigned cl, uint4 A, uint2 B) {
    float* f = facc + cl * FSTRIDE;
    float2 v;
    v = up2(A.x); atomicAdd(&f[0], v.x); atomicAdd(&f[1], v.y);
    v = up2(A.y); atomicAdd(&f[2], v.x); atomicAdd(&f[3], v.y);
    v = up2(A.z); atomicAdd(&f[4], v.x); atomicAdd(&f[5], v.y);
    v = up2(A.w); atomicAdd(&f[6], v.x); atomicAdd(&f[7], v.y);
    v = up2(B.x); atomicAdd(&f[8], v.x); atomicAdd(&f[9], v.y);
    v = up2(B.y); atomicAdd(&f[10], v.x);
}

// ---- layer 2 per bucket: per-thread fp16 gather (1 line) + LDS accumulate; pool fused ----
__global__ __launch_bounds__(256) void layer2_kernel(const unsigned* __restrict__ part,
                                                     const unsigned* __restrict__ bstart,
                                                     const ushort* __restrict__ zmsg,
                                                     const float* __restrict__ b2,
                                                     float* __restrict__ gpool) {
    __shared__ float facc[NB * FSTRIDE];           // 6.7 KB
    __shared__ float sb2[H2];
    __shared__ float gacc[7][4];
    if (threadIdx.x < H2) sb2[threadIdx.x] = b2[threadIdx.x];
    if (threadIdx.x < 28) ((float*)gacc)[threadIdx.x] = 0.f;
    __syncthreads();
    int base = blockIdx.x * NB;
    // init: own-bucket rows, self-loop + bias (deg*b2); rows >= N_NODES are garbage
    // but guarded out in the pooling phase.
    for (int n = threadIdx.x; n < NB; n += 256) {
        const ushort* zp = zmsg + (size_t)(base + n) * ZS;
        uint4 A = *(const uint4*)zp;
        uint2 B = *(const uint2*)(zp + 8);
        float2 vd = up2(B.y);
        float deg = vd.y;
        float* f = facc + n * FSTRIDE;
        float2 v;
        v = up2(A.x); f[0] = v.x + deg*sb2[0]; f[1] = v.y + deg*sb2[1];
        v = up2(A.y); f[2] = v.x + deg*sb2[2]; f[3] = v.y + deg*sb2[3];
        v = up2(A.z); f[4] = v.x + deg*sb2[4]; f[5] = v.y + deg*sb2[5];
        v = up2(A.w); f[6] = v.x + deg*sb2[6]; f[7] = v.y + deg*sb2[7];
        v = up2(B.x); f[8] = v.x + deg*sb2[8]; f[9] = v.y + deg*sb2[9];
        f[10] = vd.x + deg*sb2[10];
    }
    __syncthreads();
    // edge accumulation: one edge per thread, single-line 24B gather, unroll x2
    unsigned s = bstart[blockIdx.x], e = bstart[blockIdx.x + 1];
    unsigned i = s + threadIdx.x;
    for (; i + 256 < e; i += 512) {
        unsigned u1 = part[i], u2 = part[i + 256];
        unsigned r1 = u1 >> 7, cl1 = u1 & 127u;
        unsigned r2 = u2 >> 7, cl2 = u2 & 127u;
        const ushort* p1 = zmsg + (size_t)r1 * ZS;
        const ushort* p2 = zmsg + (size_t)r2 * ZS;
        uint4 A1 = *(const uint4*)p1; uint2 B1 = *(const uint2*)(p1 + 8);
        uint4 A2 = *(const uint4*)p2; uint2 B2 = *(const uint2*)(p2 + 8);
        acc_edge(facc, cl1, A1, B1);
        acc_edge(facc, cl2, A2, B2);
    }
    if (i < e) {
        unsigned u = part[i];
        unsigned r = u >> 7, cl = u & 127u;
        const ushort* p = zmsg + (size_t)r * ZS;
        uint4 A = *(const uint4*)p; uint2 B = *(const uint2*)(p + 8);
        acc_edge(facc, cl, A, B);
    }
    __syncthreads();
    // tanh + maxpool + per-graph partial sums (LDS), then few global atomics
    int gfirst = base / GRAPH_NODES;
    int lastnode = min(base + NB - 1, N_NODES - 1);
    int glast = lastnode / GRAPH_NODES;
    for (int n = threadIdx.x; n < NB; n += 256) {
        int node = base + n;
        if (node >= N_NODES) continue;
        const float* h = facc + n * FSTRIDE;
        float p0 = tanhf(fmaxf(h[0], h[1]));
        float p1 = tanhf(fmaxf(fmaxf(h[2], h[3]), h[4]));
        float p2 = tanhf(fmaxf(fmaxf(h[5], h[6]), h[7]));
        float p3 = tanhf(fmaxf(fmaxf(h[8], h[9]), h[10]));
        int lg = node / GRAPH_NODES - gfirst;
        atomicAdd(&gacc[lg][0], p0);
        atomicAdd(&gacc[lg][1], p1);
        atomicAdd(&gacc[lg][2], p2);
        atomicAdd(&gacc[lg][3], p3);
    }
    __syncthreads();
    int ng = glast - gfirst + 1;
    for (int t = threadIdx.x; t < ng * 4; t += 256) {
        int lg = t >> 2, c = t & 3;
        float v = gacc[lg][c];
        if (v != 0.f) atomicAdd(&gpool[(size_t)(gfirst + lg) * 4 + c], v);
    }
}

// ---- final: linear + softmax per graph ----
__global__ __launch_bounds__(256) void final_kernel(const float* __restrict__ gpool,
                                                    const float* __restrict__ Wl,
                                                    const float* __restrict__ bl,
                                                    float* __restrict__ out) {
    int g = blockIdx.x * 256 + threadIdx.x;
    if (g >= N_GRAPHS) return;
    float4 p = ((const float4*)gpool)[g];
    float o0 = bl[0] + p.x * Wl[0] + p.y * Wl[1] + p.z * Wl[2] + p.w * Wl[3];
    float o1 = bl[1] + p.x * Wl[4] + p.y * Wl[5] + p.z * Wl[6] + p.w * Wl[7];
    float m = fmaxf(o0, o1);
    float e0 = expf(o0 - m), e1 = expf(o1 - m);
    float s = e0 + e1;
    out[g * 2 + 0] = e0 / s;
    out[g * 2 + 1] = e1 / s;
}

extern "C" void kernel_launch(void* const* d_in, const int* in_sizes, int n_in,
                              void* d_out, int out_size, void* d_ws, size_t ws_size,
                              hipStream_t stream) {
    const float* x  = (const float*)d_in[0];
    const int* ei   = (const int*)d_in[1];
    const float* W1 = (const float*)d_in[2];
    const float* b1 = (const float*)d_in[3];
    const float* W2 = (const float*)d_in[4];
    const float* b2 = (const float*)d_in[5];
    const float* Wl = (const float*)d_in[6];
    const float* bl = (const float*)d_in[7];
    float* out = (float*)d_out;

    const int* row = ei;            // edge_index[0] (source)
    const int* col = ei + N_EDGES;  // edge_index[1] (destination)

    // ws layout: zmsg 8.32 MB (fp16 rows, 32 B/node) | part 33.3 MB |
    //            bstart/bfill/ghist ~24 KB | gpool 160 KB  => ~41.8 MB
    ushort*   zmsg   = (ushort*)d_ws;
    unsigned* part   = (unsigned*)((char*)d_ws + (size_t)NBUCK * NB * ZS * 2);
    unsigned* bstart = part + N_EDGES;
    unsigned* bfill  = bstart + NBUCK + 1;
    unsigned* ghist  = bfill + NBUCK;
    float*    gpool  = (float*)(ghist + NBUCK);

    zero_kernel<<<(N_GRAPHS*4 + 255)/256, 256, 0, stream>>>(ghist, gpool);
    count_kernel<<<NPB, PBT, 0, stream>>>(col, ghist);
    scan_kernel<<<1, 1024, 0, stream>>>(ghist, bstart, bfill);
    place_kernel<<<NPB, PBT, 0, stream>>>(row, col, bfill, part);
    layer1_kernel<<<NBUCK, 256, 0, stream>>>(part, bstart, x, W1, b1, W2, b2, zmsg);
    layer2_kernel<<<NBUCK, 256, 0, stream>>>(part, bstart, zmsg, b2, gpool);
    final_kernel<<<(N_GRAPHS + 255)/256, 256, 0, stream>>>(gpool, Wl, bl, out);
}